// Round 4
// baseline (123.023 us; speedup 1.0000x reference)
//
#include <hip/hip_runtime.h>

#define R_DIM 2048
#define O_DIM 32
#define I_DIM 16
#define B_DIM 64
#define BB 32   // batch rows per block (64 KB LDS, 2 blocks/CU, all-wave phase 2)

typedef _Float16 half4  __attribute__((ext_vector_type(4)));
typedef float    f32x4  __attribute__((ext_vector_type(4)));

struct SplitH4 { half4 h1, h2; };

// 2-way fp16 split of 4 consecutive fp32: x = h1 + h2 + O(2^-22 * x).
// Proven primitive sequence (cvt_pkrtz + f32 sub + cvt_pkrtz).
__device__ __forceinline__ SplitH4 splitf16x4(const float* __restrict__ p) {
    const float4 f = *(const float4*)p;
    const auto a0 = __builtin_amdgcn_cvt_pkrtz(f.x, f.y);
    const auto a1 = __builtin_amdgcn_cvt_pkrtz(f.z, f.w);
    const auto c0 = __builtin_amdgcn_cvt_pkrtz(f.x - (float)a0[0], f.y - (float)a0[1]);
    const auto c1 = __builtin_amdgcn_cvt_pkrtz(f.z - (float)a1[0], f.w - (float)a1[1]);
    SplitH4 s;
    s.h1[0] = (_Float16)a0[0]; s.h1[1] = (_Float16)a0[1];
    s.h1[2] = (_Float16)a1[0]; s.h1[3] = (_Float16)a1[1];
    s.h2[0] = (_Float16)c0[0]; s.h2[1] = (_Float16)c0[1];
    s.h2[2] = (_Float16)c1[0]; s.h2[3] = (_Float16)c1[1];
    return s;
}

// DPP helpers — all stay on the VALU pipe (no DS traffic).
template<int CTRL>
__device__ __forceinline__ float dpp_mv(float v) {
    int t = __builtin_amdgcn_update_dpp(0, __float_as_int(v), CTRL, 0xf, 0xf, true);
    return __int_as_float(t);
}
__device__ __forceinline__ float row16_sum(float v) {
    v += dpp_mv<0xB1>(v);    // quad_perm xor1
    v += dpp_mv<0x4E>(v);    // quad_perm xor2
    v += dpp_mv<0x124>(v);   // row_ror:4
    v += dpp_mv<0x128>(v);   // row_ror:8
    return v;
}
__device__ __forceinline__ float row16_max(float v) {
    v = fmaxf(v, dpp_mv<0xB1>(v));
    v = fmaxf(v, dpp_mv<0x4E>(v));
    v = fmaxf(v, dpp_mv<0x124>(v));
    v = fmaxf(v, dpp_mv<0x128>(v));
    return v;
}
// row_ror:N — dst[n] = src[(n-N)&15]
__device__ __forceinline__ float ror1(float v) { return dpp_mv<0x121>(v); }
__device__ __forceinline__ float ror2(float v) { return dpp_mv<0x122>(v); }
__device__ __forceinline__ float ror3(float v) { return dpp_mv<0x123>(v); }
__device__ __forceinline__ float ror4(float v) { return dpp_mv<0x124>(v); }

// Block: 512 threads = 8 waves; one (r, 32-batch slice); 64 KB LDS ->
// 2 blocks/CU, 16 waves/CU — ALL waves useful in both phases (the BB=16
// version parked 4 waves holding LDS through phase 2).
// Phase 1 (all 8 waves): u_hat[32b x 512n]; each wave: 4 n-tiles x 2 m-tiles,
//   W split once per n-tile, reused across m-tiles (halves W-split work).
// Phase 2 (all 512 threads): thread=(b,j) owns o={2j,2j+1}; lane j holds
//   logit bv[c=j]; QUAD ror4 systolic chains -> 4x DPP-dependency ILP.
// Swizzle: position = row*512 + (n ^ sw), sw(row) = ((row^(row>>2))&3)<<3.
__global__ __launch_bounds__(512, 4)
void capsule_routing_kernel(const float* __restrict__ x,
                            const float* __restrict__ W,
                            float* __restrict__ out) {
    __shared__ float u_lds[BB * 512];   // 64 KB

    const int tid = threadIdx.x;
    // XCD-grouping remap: the 2 batch-slice blocks of one r are 8 apart
    // -> same XCD (round-robin %8) -> W[r]'s 32 KB fetched once per r.
    const int bid = blockIdx.x;
    const int r   = ((bid >> 4) << 3) | (bid & 7);
    const int b0  = ((bid >> 3) & 1) * BB;

    // ---------------- Phase 1: fp16-split MFMA u_hat ----------------
    {
        const int lane = tid & 63;
        const int w    = tid >> 6;     // wave 0..7 -> n-tiles 4w..4w+3
        const int q    = lane >> 4;    // k-quad 0..3 (all valid, K=16)
        const int np   = lane & 15;    // m (batch) for A / n-col for B

        const SplitH4 as0 = splitf16x4(x + ((size_t)(b0 + np)      * R_DIM + r) * I_DIM + q * 4);
        const SplitH4 as1 = splitf16x4(x + ((size_t)(b0 + 16 + np) * R_DIM + r) * I_DIM + q * 4);

        const float* Wbase = W + (size_t)r * 8192 + (size_t)(w * 4) * 256 + np * 16 + q * 4;

        const f32x4 zero4 = {0.f, 0.f, 0.f, 0.f};
        #pragma unroll
        for (int t = 0; t < 4; ++t) {
            const int ntile = w * 4 + t;
            const SplitH4 bs = splitf16x4(Wbase + t * 256);

            const int col = ntile * 16 + np;
            const int v0  = col ^ (q << 3);

            // m-tile 0 (batch rows 0..15): row = 4q+reg, sw = ((reg^q)&3)<<3
            f32x4 a = __builtin_amdgcn_mfma_f32_16x16x16f16(as0.h2, bs.h1, zero4, 0, 0, 0);
            a = __builtin_amdgcn_mfma_f32_16x16x16f16(as0.h1, bs.h2, a, 0, 0, 0);
            a = __builtin_amdgcn_mfma_f32_16x16x16f16(as0.h1, bs.h1, a, 0, 0, 0);
            float* pb = u_lds + q * 2048;
            pb[v0]               = a[0];
            pb[512  + (v0 ^ 8)]  = a[1];
            pb[1024 + (v0 ^ 16)] = a[2];
            pb[1536 + (v0 ^ 24)] = a[3];

            // m-tile 1 (batch rows 16..31): row = 16+4q+reg, same sw (mt-indep.)
            f32x4 c = __builtin_amdgcn_mfma_f32_16x16x16f16(as1.h2, bs.h1, zero4, 0, 0, 0);
            c = __builtin_amdgcn_mfma_f32_16x16x16f16(as1.h1, bs.h2, c, 0, 0, 0);
            c = __builtin_amdgcn_mfma_f32_16x16x16f16(as1.h1, bs.h1, c, 0, 0, 0);
            float* pc = u_lds + 8192 + q * 2048;
            pc[v0]               = c[0];
            pc[512  + (v0 ^ 8)]  = c[1];
            pc[1024 + (v0 ^ 16)] = c[2];
            pc[1536 + (v0 ^ 24)] = c[3];
        }
    }
    __syncthreads();

    // ---------------- Phase 2: systolic dynamic routing (all 512 lanes) -------
    {
        const int b = tid >> 4;    // 0..31 local batch (one DPP row per b)
        const int j = tid & 15;    // o-pair index / owner of logit c=j

        const int sw  = ((b ^ (b >> 2)) & 3) << 3;         // even -> b64-aligned
        const int pxB = (b * 512 + ((2 * j) ^ sw)) * 4;    // byte addr, c=0
        const char* base = (const char*)u_lds;

        // X[k] = {u[c=(j-k)&15][o0], u[c][o1]} — b64 pair loads; c-field =
        // addr bits 7..10 walks down via (t -= 128) & 0x780 (two's-compl wrap).
        float2 X[16];
        {
            int t = j * 128;
            #pragma unroll
            for (int k = 0; k < 16; ++k) {
                X[k] = *(const float2*)(base + ((t & 0x780) | pxB));
                t -= 128;
            }
        }

        float bvv = 0.0f;          // logit for c=j (distributed)
        float s0 = 0.f, s1 = 0.f, g = 0.f;

        #pragma unroll
        for (int it = 0; it < 3; ++it) {
            if (it == 0) {
                // uniform weights: mean over c, explicit add trees
                const float e0 = (X[0].x + X[1].x) + (X[2].x  + X[3].x);
                const float e1 = (X[4].x + X[5].x) + (X[6].x  + X[7].x);
                const float e2 = (X[8].x + X[9].x) + (X[10].x + X[11].x);
                const float e3 = (X[12].x + X[13].x) + (X[14].x + X[15].x);
                const float f0 = (X[0].y + X[1].y) + (X[2].y  + X[3].y);
                const float f1 = (X[4].y + X[5].y) + (X[6].y  + X[7].y);
                const float f2 = (X[8].y + X[9].y) + (X[10].y + X[11].y);
                const float f3 = (X[12].y + X[13].y) + (X[14].y + X[15].y);
                s0 = ((e0 + e1) + (e2 + e3)) * 0.0625f;
                s1 = ((f0 + f1) + (f2 + f3)) * 0.0625f;
            } else {
                // softmax at lane c: 1 exp/thread
                const float mx = row16_max(bvv);
                const float e  = __expf(bvv - mx);
                const float Z  = row16_sum(e);
                const float wr = e * __builtin_amdgcn_rcpf(Z);   // w_c at lane c
                // s_o = sum_c w_c u[c][o]; QUAD chains: chain i handles
                // k = i+4m, weight W_i at step m = w_{j-i-4m} (seed ror_i, step ror4)
                float W0 = wr, W1 = ror1(wr), W2 = ror2(wr), W3 = ror3(wr);
                float sA0 = 0.f, sA1 = 0.f, sB0 = 0.f, sB1 = 0.f;
                float sC0 = 0.f, sC1 = 0.f, sD0 = 0.f, sD1 = 0.f;
                #pragma unroll
                for (int m = 0; m < 4; ++m) {
                    if (m) { W0 = ror4(W0); W1 = ror4(W1); W2 = ror4(W2); W3 = ror4(W3); }
                    sA0 = fmaf(W0, X[4*m].x,     sA0); sA1 = fmaf(W0, X[4*m].y,     sA1);
                    sB0 = fmaf(W1, X[4*m + 1].x, sB0); sB1 = fmaf(W1, X[4*m + 1].y, sB1);
                    sC0 = fmaf(W2, X[4*m + 2].x, sC0); sC1 = fmaf(W2, X[4*m + 2].y, sC1);
                    sD0 = fmaf(W3, X[4*m + 3].x, sD0); sD1 = fmaf(W3, X[4*m + 3].y, sD1);
                }
                s0 = (sA0 + sB0) + (sC0 + sD0);
                s1 = (sA1 + sB1) + (sC1 + sD1);
            }

            // g = ||s|| / (1 + ||s||^2), norm over 32 o's (16 j-lanes x 2)
            const float nn = row16_sum(fmaf(s0, s0, s1 * s1));
            g = sqrtf(nn) * __builtin_amdgcn_rcpf(1.0f + nn);

            if (it < 2) {
                // t[c] = sum_o u[c][o] s[o] via QUAD rotating accumulators.
                // Chain i, step m adds the term destined for c = j-i-4m; it
                // then gets 4(3-m) in-loop rors; need total 16-i-4m -> final
                // ror(4-i): A:ror4, B:ror3, C:ror2, D:ror1.
                float aA = 0.f, aB = 0.f, aC = 0.f, aD = 0.f;
                #pragma unroll
                for (int m = 0; m < 4; ++m) {
                    if (m) { aA = ror4(aA); aB = ror4(aB); aC = ror4(aC); aD = ror4(aD); }
                    aA = fmaf(X[4*m].x,     s0, aA); aA = fmaf(X[4*m].y,     s1, aA);
                    aB = fmaf(X[4*m + 1].x, s0, aB); aB = fmaf(X[4*m + 1].y, s1, aB);
                    aC = fmaf(X[4*m + 2].x, s0, aC); aC = fmaf(X[4*m + 2].y, s1, aC);
                    aD = fmaf(X[4*m + 3].x, s0, aD); aD = fmaf(X[4*m + 3].y, s1, aD);
                }
                const float acc = (ror4(aA) + ror3(aB)) + (ror2(aC) + ror1(aD));
                bvv = fmaf(g, acc, bvv);   // b[c] += g * t[c]
            }
        }

        *(float2*)(out + ((size_t)(b0 + b) * R_DIM + r) * O_DIM + 2 * j)
            = make_float2(g * s0, g * s1);
    }
}

extern "C" void kernel_launch(void* const* d_in, const int* in_sizes, int n_in,
                              void* d_out, int out_size, void* d_ws, size_t ws_size,
                              hipStream_t stream) {
    const float* x   = (const float*)d_in[0];   // [64, 2048, 16]
    const float* W   = (const float*)d_in[1];   // [2048, 16, 32, 16]
    float*       out = (float*)d_out;           // [64, 2048, 32]

    dim3 grid(R_DIM * (B_DIM / BB));            // 4096 blocks
    dim3 block(512);
    hipLaunchKernelGGL(capsule_routing_kernel, grid, block, 0, stream, x, W, out);
}

// Round 5
// 122.801 us; speedup vs baseline: 1.0018x; 1.0018x over previous
//
#include <hip/hip_runtime.h>

#define R_DIM 2048
#define O_DIM 32
#define I_DIM 16
#define B_DIM 64
#define BB 32   // batch rows per block (64 KB LDS, 2 blocks/CU, all-wave phase 2)

typedef _Float16 half4  __attribute__((ext_vector_type(4)));
typedef float    f32x4  __attribute__((ext_vector_type(4)));

struct SplitH4 { half4 h1, h2; };

// 2-way fp16 split of 4 consecutive fp32: x = h1 + h2 + O(2^-22 * x).
// h1 via packed cvt (RTZ); residual via v_fma_mix (f32-precision fma with an
// f16 source half selected by op_sel, RNE-rounded into one f16 half of the
// dest): 6 VALU per split vs 12 for the cvt+sub+cvt_pkrtz path.
__device__ __forceinline__ SplitH4 splitf16x4(const float* __restrict__ p) {
    const float4 f = *(const float4*)p;
    const auto a0 = __builtin_amdgcn_cvt_pkrtz(f.x, f.y);
    const auto a1 = __builtin_amdgcn_cvt_pkrtz(f.z, f.w);
    int ab0, ab1;
    __builtin_memcpy(&ab0, &a0, 4);
    __builtin_memcpy(&ab1, &a1, 4);
    int r0, r1;
    // r0.lo = f16(f.x - h1(f.x)), r0.hi = f16(f.y - h1(f.y)), etc.
    asm("v_fma_mixlo_f16 %0, %1, -1.0, %2 op_sel_hi:[1,0,0]"
        : "=v"(r0) : "v"(ab0), "v"(f.x));
    asm("v_fma_mixhi_f16 %0, %1, -1.0, %2 op_sel:[1,0,0] op_sel_hi:[1,0,0]"
        : "+v"(r0) : "v"(ab0), "v"(f.y));
    asm("v_fma_mixlo_f16 %0, %1, -1.0, %2 op_sel_hi:[1,0,0]"
        : "=v"(r1) : "v"(ab1), "v"(f.z));
    asm("v_fma_mixhi_f16 %0, %1, -1.0, %2 op_sel:[1,0,0] op_sel_hi:[1,0,0]"
        : "+v"(r1) : "v"(ab1), "v"(f.w));
    union U { int i[2]; half4 h; };
    U u1, u2;
    u1.i[0] = ab0; u1.i[1] = ab1;
    u2.i[0] = r0;  u2.i[1] = r1;
    SplitH4 s; s.h1 = u1.h; s.h2 = u2.h;
    return s;
}

// DPP helpers — all stay on the VALU pipe (no DS traffic).
template<int CTRL>
__device__ __forceinline__ float dpp_mv(float v) {
    int t = __builtin_amdgcn_update_dpp(0, __float_as_int(v), CTRL, 0xf, 0xf, true);
    return __int_as_float(t);
}
__device__ __forceinline__ float row16_sum(float v) {
    v += dpp_mv<0xB1>(v);    // quad_perm xor1
    v += dpp_mv<0x4E>(v);    // quad_perm xor2
    v += dpp_mv<0x124>(v);   // row_ror:4
    v += dpp_mv<0x128>(v);   // row_ror:8
    return v;
}
__device__ __forceinline__ float row16_max(float v) {
    v = fmaxf(v, dpp_mv<0xB1>(v));
    v = fmaxf(v, dpp_mv<0x4E>(v));
    v = fmaxf(v, dpp_mv<0x124>(v));
    v = fmaxf(v, dpp_mv<0x128>(v));
    return v;
}
// row_ror:N — dst[n] = src[(n-N)&15]
__device__ __forceinline__ float ror1(float v) { return dpp_mv<0x121>(v); }
__device__ __forceinline__ float ror2(float v) { return dpp_mv<0x122>(v); }
__device__ __forceinline__ float ror3(float v) { return dpp_mv<0x123>(v); }
__device__ __forceinline__ float ror4(float v) { return dpp_mv<0x124>(v); }

// Block: 512 threads = 8 waves; one (r, 32-batch slice); 64 KB LDS ->
// 2 blocks/CU. Phase 1: u_hat via 3-term fp16-split MFMA 16x16x16, W split
// once per block. Phase 2 (all 512 threads): thread=(b,j) owns o={2j,2j+1};
// lane j holds logit bv[c=j] (pre-scaled by log2e -> exp2 softmax); QUAD
// ror4 systolic chains. s_setprio(1) keeps phase-2 latency chains winning
// issue arbitration against the co-resident block's phase-1 streams.
__global__ __launch_bounds__(512, 4)
void capsule_routing_kernel(const float* __restrict__ x,
                            const float* __restrict__ W,
                            float* __restrict__ out) {
    __shared__ float u_lds[BB * 512];   // 64 KB

    const int tid = threadIdx.x;
    // XCD-grouping remap: the 2 batch-slice blocks of one r are 8 apart
    // -> same XCD (round-robin %8) -> W[r]'s 32 KB fetched once per r.
    const int bid = blockIdx.x;
    const int r   = ((bid >> 4) << 3) | (bid & 7);
    const int b0  = ((bid >> 3) & 1) * BB;

    // ---------------- Phase 1: fp16-split MFMA u_hat ----------------
    {
        const int lane = tid & 63;
        const int w    = tid >> 6;     // wave 0..7 -> n-tiles 4w..4w+3
        const int q    = lane >> 4;    // k-quad 0..3 (all valid, K=16)
        const int np   = lane & 15;    // m (batch) for A / n-col for B

        const SplitH4 as0 = splitf16x4(x + ((size_t)(b0 + np)      * R_DIM + r) * I_DIM + q * 4);
        const SplitH4 as1 = splitf16x4(x + ((size_t)(b0 + 16 + np) * R_DIM + r) * I_DIM + q * 4);

        const float* Wbase = W + (size_t)r * 8192 + (size_t)(w * 4) * 256 + np * 16 + q * 4;

        const f32x4 zero4 = {0.f, 0.f, 0.f, 0.f};
        #pragma unroll
        for (int t = 0; t < 4; ++t) {
            const int ntile = w * 4 + t;
            const SplitH4 bs = splitf16x4(Wbase + t * 256);

            const int col = ntile * 16 + np;
            const int v0  = col ^ (q << 3);

            // m-tile 0 (batch rows 0..15): row = 4q+reg, sw = ((reg^q)&3)<<3
            f32x4 a = __builtin_amdgcn_mfma_f32_16x16x16f16(as0.h2, bs.h1, zero4, 0, 0, 0);
            a = __builtin_amdgcn_mfma_f32_16x16x16f16(as0.h1, bs.h2, a, 0, 0, 0);
            a = __builtin_amdgcn_mfma_f32_16x16x16f16(as0.h1, bs.h1, a, 0, 0, 0);
            float* pb = u_lds + q * 2048;
            pb[v0]               = a[0];
            pb[512  + (v0 ^ 8)]  = a[1];
            pb[1024 + (v0 ^ 16)] = a[2];
            pb[1536 + (v0 ^ 24)] = a[3];

            // m-tile 1 (batch rows 16..31): row = 16+4q+reg, same sw (mt-indep.)
            f32x4 c = __builtin_amdgcn_mfma_f32_16x16x16f16(as1.h2, bs.h1, zero4, 0, 0, 0);
            c = __builtin_amdgcn_mfma_f32_16x16x16f16(as1.h1, bs.h2, c, 0, 0, 0);
            c = __builtin_amdgcn_mfma_f32_16x16x16f16(as1.h1, bs.h1, c, 0, 0, 0);
            float* pc = u_lds + 8192 + q * 2048;
            pc[v0]               = c[0];
            pc[512  + (v0 ^ 8)]  = c[1];
            pc[1024 + (v0 ^ 16)] = c[2];
            pc[1536 + (v0 ^ 24)] = c[3];
        }
    }
    __syncthreads();
    __builtin_amdgcn_s_setprio(1);

    // ---------------- Phase 2: systolic dynamic routing (all 512 lanes) -------
    {
        const int b = tid >> 4;    // 0..31 local batch (one DPP row per b)
        const int j = tid & 15;    // o-pair index / owner of logit c=j

        const int sw  = ((b ^ (b >> 2)) & 3) << 3;         // even -> b64-aligned
        const int pxB = (b * 512 + ((2 * j) ^ sw)) * 4;    // byte addr, c=0
        const char* base = (const char*)u_lds;

        // X[k] = {u[c=(j-k)&15][o0], u[c][o1]} — b64 pair loads; c-field =
        // addr bits 7..10 walks down via (t -= 128) & 0x780 (two's-compl wrap).
        float2 X[16];
        {
            int t = j * 128;
            #pragma unroll
            for (int k = 0; k < 16; ++k) {
                X[k] = *(const float2*)(base + ((t & 0x780) | pxB));
                t -= 128;
            }
        }

        float bvv = 0.0f;          // log2e-scaled logit for c=j (distributed)
        float s0 = 0.f, s1 = 0.f, g = 0.f;

        #pragma unroll
        for (int it = 0; it < 3; ++it) {
            if (it == 0) {
                // uniform weights: mean over c, explicit add trees
                const float e0 = (X[0].x + X[1].x) + (X[2].x  + X[3].x);
                const float e1 = (X[4].x + X[5].x) + (X[6].x  + X[7].x);
                const float e2 = (X[8].x + X[9].x) + (X[10].x + X[11].x);
                const float e3 = (X[12].x + X[13].x) + (X[14].x + X[15].x);
                const float f0 = (X[0].y + X[1].y) + (X[2].y  + X[3].y);
                const float f1 = (X[4].y + X[5].y) + (X[6].y  + X[7].y);
                const float f2 = (X[8].y + X[9].y) + (X[10].y + X[11].y);
                const float f3 = (X[12].y + X[13].y) + (X[14].y + X[15].y);
                s0 = ((e0 + e1) + (e2 + e3)) * 0.0625f;
                s1 = ((f0 + f1) + (f2 + f3)) * 0.0625f;
            } else {
                // softmax at lane c (base 2; logits pre-scaled by log2e)
                const float mx = row16_max(bvv);
                const float e  = exp2f(bvv - mx);
                const float Z  = row16_sum(e);
                const float wr = e * __builtin_amdgcn_rcpf(Z);   // w_c at lane c
                // s_o = sum_c w_c u[c][o]; QUAD chains: chain i handles
                // k = i+4m, weight W_i at step m = w_{j-i-4m} (seed ror_i, step ror4)
                float W0 = wr, W1 = ror1(wr), W2 = ror2(wr), W3 = ror3(wr);
                float sA0 = 0.f, sA1 = 0.f, sB0 = 0.f, sB1 = 0.f;
                float sC0 = 0.f, sC1 = 0.f, sD0 = 0.f, sD1 = 0.f;
                #pragma unroll
                for (int m = 0; m < 4; ++m) {
                    if (m) { W0 = ror4(W0); W1 = ror4(W1); W2 = ror4(W2); W3 = ror4(W3); }
                    sA0 = fmaf(W0, X[4*m].x,     sA0); sA1 = fmaf(W0, X[4*m].y,     sA1);
                    sB0 = fmaf(W1, X[4*m + 1].x, sB0); sB1 = fmaf(W1, X[4*m + 1].y, sB1);
                    sC0 = fmaf(W2, X[4*m + 2].x, sC0); sC1 = fmaf(W2, X[4*m + 2].y, sC1);
                    sD0 = fmaf(W3, X[4*m + 3].x, sD0); sD1 = fmaf(W3, X[4*m + 3].y, sD1);
                }
                s0 = (sA0 + sB0) + (sC0 + sD0);
                s1 = (sA1 + sB1) + (sC1 + sD1);
            }

            // g = ||s|| / (1 + ||s||^2), norm over 32 o's (16 j-lanes x 2)
            const float nn = row16_sum(fmaf(s0, s0, s1 * s1));
            g = sqrtf(nn) * __builtin_amdgcn_rcpf(1.0f + nn);

            if (it < 2) {
                // t[c] = sum_o u[c][o] s[o] via QUAD rotating accumulators.
                // Chain i, step m adds the term destined for c = j-i-4m; it
                // then gets 4(3-m) in-loop rors; need total 16-i-4m -> final
                // ror(4-i): A:ror4, B:ror3, C:ror2, D:ror1.
                float aA = 0.f, aB = 0.f, aC = 0.f, aD = 0.f;
                #pragma unroll
                for (int m = 0; m < 4; ++m) {
                    if (m) { aA = ror4(aA); aB = ror4(aB); aC = ror4(aC); aD = ror4(aD); }
                    aA = fmaf(X[4*m].x,     s0, aA); aA = fmaf(X[4*m].y,     s1, aA);
                    aB = fmaf(X[4*m + 1].x, s0, aB); aB = fmaf(X[4*m + 1].y, s1, aB);
                    aC = fmaf(X[4*m + 2].x, s0, aC); aC = fmaf(X[4*m + 2].y, s1, aC);
                    aD = fmaf(X[4*m + 3].x, s0, aD); aD = fmaf(X[4*m + 3].y, s1, aD);
                }
                const float acc = (ror4(aA) + ror3(aB)) + (ror2(aC) + ror1(aD));
                // b[c] += g*log2e * t[c]  (keeps logits in base-2 domain)
                bvv = fmaf(g * 1.44269504f, acc, bvv);
            }
        }

        __builtin_amdgcn_s_setprio(0);
        *(float2*)(out + ((size_t)(b0 + b) * R_DIM + r) * O_DIM + 2 * j)
            = make_float2(g * s0, g * s1);
    }
}

extern "C" void kernel_launch(void* const* d_in, const int* in_sizes, int n_in,
                              void* d_out, int out_size, void* d_ws, size_t ws_size,
                              hipStream_t stream) {
    const float* x   = (const float*)d_in[0];   // [64, 2048, 16]
    const float* W   = (const float*)d_in[1];   // [2048, 16, 32, 16]
    float*       out = (float*)d_out;           // [64, 2048, 32]

    dim3 grid(R_DIM * (B_DIM / BB));            // 4096 blocks
    dim3 block(512);
    hipLaunchKernelGGL(capsule_routing_kernel, grid, block, 0, stream, x, W, out);
}

// Round 6
// 120.251 us; speedup vs baseline: 1.0230x; 1.0212x over previous
//
#include <hip/hip_runtime.h>

#define R_DIM 2048
#define O_DIM 32
#define I_DIM 16
#define B_DIM 64
#define BB 32   // batch rows per tile (two tiles = both slices of one r per block)

typedef _Float16 half4  __attribute__((ext_vector_type(4)));
typedef float    f32x4  __attribute__((ext_vector_type(4)));

struct SplitH4 { half4 h1, h2; };

// 2-way fp16 split of 4 fp32: x = h1 + h2 + O(2^-22 x). h1 via packed cvt
// (RTZ); residual via v_fma_mix (proven round 5: absmax 0.00195).
__device__ __forceinline__ SplitH4 splitf16v(const float4 f) {
    const auto a0 = __builtin_amdgcn_cvt_pkrtz(f.x, f.y);
    const auto a1 = __builtin_amdgcn_cvt_pkrtz(f.z, f.w);
    int ab0, ab1;
    __builtin_memcpy(&ab0, &a0, 4);
    __builtin_memcpy(&ab1, &a1, 4);
    int r0, r1;
    asm("v_fma_mixlo_f16 %0, %1, -1.0, %2 op_sel_hi:[1,0,0]"
        : "=v"(r0) : "v"(ab0), "v"(f.x));
    asm("v_fma_mixhi_f16 %0, %1, -1.0, %2 op_sel:[1,0,0] op_sel_hi:[1,0,0]"
        : "+v"(r0) : "v"(ab0), "v"(f.y));
    asm("v_fma_mixlo_f16 %0, %1, -1.0, %2 op_sel_hi:[1,0,0]"
        : "=v"(r1) : "v"(ab1), "v"(f.z));
    asm("v_fma_mixhi_f16 %0, %1, -1.0, %2 op_sel:[1,0,0] op_sel_hi:[1,0,0]"
        : "+v"(r1) : "v"(ab1), "v"(f.w));
    union U { int i[2]; half4 h; };
    U u1, u2;
    u1.i[0] = ab0; u1.i[1] = ab1;
    u2.i[0] = r0;  u2.i[1] = r1;
    SplitH4 s; s.h1 = u1.h; s.h2 = u2.h;
    return s;
}
__device__ __forceinline__ SplitH4 splitf16p(const float* __restrict__ p) {
    return splitf16v(*(const float4*)p);
}

// DPP helpers — VALU pipe only.
template<int CTRL>
__device__ __forceinline__ float dpp_mv(float v) {
    int t = __builtin_amdgcn_update_dpp(0, __float_as_int(v), CTRL, 0xf, 0xf, true);
    return __int_as_float(t);
}
__device__ __forceinline__ float row16_sum(float v) {
    v += dpp_mv<0xB1>(v);
    v += dpp_mv<0x4E>(v);
    v += dpp_mv<0x124>(v);
    v += dpp_mv<0x128>(v);
    return v;
}
__device__ __forceinline__ float row16_max(float v) {
    v = fmaxf(v, dpp_mv<0xB1>(v));
    v = fmaxf(v, dpp_mv<0x4E>(v));
    v = fmaxf(v, dpp_mv<0x124>(v));
    v = fmaxf(v, dpp_mv<0x128>(v));
    return v;
}
__device__ __forceinline__ float ror1(float v) { return dpp_mv<0x121>(v); }
__device__ __forceinline__ float ror2(float v) { return dpp_mv<0x122>(v); }
__device__ __forceinline__ float ror3(float v) { return dpp_mv<0x123>(v); }
__device__ __forceinline__ float ror4(float v) { return dpp_mv<0x124>(v); }

__device__ __forceinline__ f32x4 mfma3(const SplitH4& A, const SplitH4& B) {
    const f32x4 z = {0.f, 0.f, 0.f, 0.f};
    f32x4 a = __builtin_amdgcn_mfma_f32_16x16x16f16(A.h2, B.h1, z, 0, 0, 0);
    a = __builtin_amdgcn_mfma_f32_16x16x16f16(A.h1, B.h2, a, 0, 0, 0);
    a = __builtin_amdgcn_mfma_f32_16x16x16f16(A.h1, B.h1, a, 0, 0, 0);
    return a;
}
// Store one C column with row-swizzle: pos = row*512 + (col ^ sw(row)),
// row = 4q+reg (+16 for upper m-tile), sw = ((reg^q)&3)<<3.
__device__ __forceinline__ void storeC(float* p, int v0, const f32x4& a) {
    p[v0]               = a[0];
    p[512  + (v0 ^ 8)]  = a[1];
    p[1024 + (v0 ^ 16)] = a[2];
    p[1536 + (v0 ^ 24)] = a[3];
}

// ---- routing building blocks (round-5-proven numerics) ----
__device__ __forceinline__ void iter0_mean(const float2* X, float& s0, float& s1) {
    const float e0 = (X[0].x + X[1].x) + (X[2].x  + X[3].x);
    const float e1 = (X[4].x + X[5].x) + (X[6].x  + X[7].x);
    const float e2 = (X[8].x + X[9].x) + (X[10].x + X[11].x);
    const float e3 = (X[12].x + X[13].x) + (X[14].x + X[15].x);
    const float f0 = (X[0].y + X[1].y) + (X[2].y  + X[3].y);
    const float f1 = (X[4].y + X[5].y) + (X[6].y  + X[7].y);
    const float f2 = (X[8].y + X[9].y) + (X[10].y + X[11].y);
    const float f3 = (X[12].y + X[13].y) + (X[14].y + X[15].y);
    s0 = ((e0 + e1) + (e2 + e3)) * 0.0625f;
    s1 = ((f0 + f1) + (f2 + f3)) * 0.0625f;
}
__device__ __forceinline__ float softmax_w(float bvv) {
    const float mx = row16_max(bvv);
    const float e  = exp2f(bvv - mx);          // logits pre-scaled by log2e
    const float Z  = row16_sum(e);
    return e * __builtin_amdgcn_rcpf(Z);
}
__device__ __forceinline__ void sloop(const float2* X, float wr, float& s0, float& s1) {
    float W0 = wr, W1 = ror1(wr), W2 = ror2(wr), W3 = ror3(wr);
    float sA0 = 0.f, sA1 = 0.f, sB0 = 0.f, sB1 = 0.f;
    float sC0 = 0.f, sC1 = 0.f, sD0 = 0.f, sD1 = 0.f;
    #pragma unroll
    for (int m = 0; m < 4; ++m) {
        if (m) { W0 = ror4(W0); W1 = ror4(W1); W2 = ror4(W2); W3 = ror4(W3); }
        sA0 = fmaf(W0, X[4*m].x,     sA0); sA1 = fmaf(W0, X[4*m].y,     sA1);
        sB0 = fmaf(W1, X[4*m + 1].x, sB0); sB1 = fmaf(W1, X[4*m + 1].y, sB1);
        sC0 = fmaf(W2, X[4*m + 2].x, sC0); sC1 = fmaf(W2, X[4*m + 2].y, sC1);
        sD0 = fmaf(W3, X[4*m + 3].x, sD0); sD1 = fmaf(W3, X[4*m + 3].y, sD1);
    }
    s0 = (sA0 + sB0) + (sC0 + sD0);
    s1 = (sA1 + sB1) + (sC1 + sD1);
}
__device__ __forceinline__ float tloop(const float2* X, float s0, float s1) {
    float aA = 0.f, aB = 0.f, aC = 0.f, aD = 0.f;
    #pragma unroll
    for (int m = 0; m < 4; ++m) {
        if (m) { aA = ror4(aA); aB = ror4(aB); aC = ror4(aC); aD = ror4(aD); }
        aA = fmaf(X[4*m].x,     s0, aA); aA = fmaf(X[4*m].y,     s1, aA);
        aB = fmaf(X[4*m + 1].x, s0, aB); aB = fmaf(X[4*m + 1].y, s1, aB);
        aC = fmaf(X[4*m + 2].x, s0, aC); aC = fmaf(X[4*m + 2].y, s1, aC);
        aD = fmaf(X[4*m + 3].x, s0, aD); aD = fmaf(X[4*m + 3].y, s1, aD);
    }
    return (ror4(aA) + ror3(aB)) + (ror2(aC) + ror1(aD));
}
__device__ __forceinline__ float squash_g(float s0, float s1) {
    const float nn = row16_sum(fmaf(s0, s0, s1 * s1));
    return sqrtf(nn) * __builtin_amdgcn_rcpf(1.0f + nn);
}

// Full 3-iteration routing; chunk(t) call-sites inject the next tile's
// phase-1 work into the serial-chain gaps (F = no-op for the last tile).
template<typename F>
__device__ __forceinline__ float2 routing_run(const float2* X, F&& chunk) {
    float s0, s1;
    chunk(0);
    iter0_mean(X, s0, s1);                       // it 0: uniform weights
    float g = squash_g(s0, s1);
    chunk(1);
    float bvv = (g * 1.44269504f) * tloop(X, s0, s1);
    chunk(2);
    sloop(X, softmax_w(bvv), s0, s1);            // it 1
    g = squash_g(s0, s1);
    chunk(3);
    bvv = fmaf(g * 1.44269504f, tloop(X, s0, s1), bvv);
    sloop(X, softmax_w(bvv), s0, s1);            // it 2
    g = squash_g(s0, s1);
    return make_float2(g * s0, g * s1);
}

// Block: 512 threads, ONE r, BOTH 32-batch slices, pipelined:
//   P1(slice0) | bar | loadX0 | bar | [routing(X0) ∥ P1b(slice1)] | bar |
//   loadX1 | routing(X1).
// The overlap region mixes routing's latency-gated DPP chains with P1b's
// dependency-light MFMA/split/store stream — breaking the co-resident-block
// phase lock that pinned rounds 2-5 at ~46 µs. W splits (bs[]) are computed
// once per r and reused by both slices. 64 KB LDS -> 2 blocks/CU.
__global__ __launch_bounds__(512, 4)
void capsule_routing_kernel(const float* __restrict__ x,
                            const float* __restrict__ W,
                            float* __restrict__ out) {
    __shared__ float u_lds[BB * 512];   // 64 KB

    const int tid  = threadIdx.x;
    const int r    = blockIdx.x;
    const int lane = tid & 63;
    const int w4   = (tid >> 6) * 4;   // wave -> n-tiles w4..w4+3
    const int q    = lane >> 4;        // k-quad 0..3
    const int np   = lane & 15;        // m (batch) for A / n-col for B

    const size_t xrow  = ((size_t)np * R_DIM + r) * I_DIM + q * 4;
    const size_t bstep = (size_t)16 * R_DIM * I_DIM;
    const float* Wbase = W + (size_t)r * 8192 + (size_t)w4 * 256 + np * 16 + q * 4;

    // slice-1 x rows: load early, split later (latency hides under P1).
    const float4 xf1a = *(const float4*)(x + xrow + 2 * bstep);
    const float4 xf1b = *(const float4*)(x + xrow + 3 * bstep);

    // ---------------- Phase 1, slice 0 ----------------
    SplitH4 bs[4];
    {
        const SplitH4 as0a = splitf16p(x + xrow);
        const SplitH4 as0b = splitf16p(x + xrow + bstep);
        #pragma unroll
        for (int t = 0; t < 4; ++t) bs[t] = splitf16p(Wbase + t * 256);
        #pragma unroll
        for (int t = 0; t < 4; ++t) {
            const int v0 = ((w4 + t) * 16 + np) ^ (q << 3);
            storeC(u_lds + q * 2048,        v0, mfma3(as0a, bs[t]));
            storeC(u_lds + 8192 + q * 2048, v0, mfma3(as0b, bs[t]));
        }
    }
    __syncthreads();

    // ---------------- Phase 2 indexing ----------------
    const int b = tid >> 4;    // 0..31 local batch
    const int j = tid & 15;    // o-pair index / logit owner c=j
    const int sw  = ((b ^ (b >> 2)) & 3) << 3;
    const int pxB = (b * 512 + ((2 * j) ^ sw)) * 4;
    const char* base = (const char*)u_lds;

    #define LOADX(X)                                                   \
        {                                                              \
            int tt = j * 128;                                          \
            _Pragma("unroll")                                          \
            for (int k = 0; k < 16; ++k) {                             \
                X[k] = *(const float2*)(base + ((tt & 0x780) | pxB));  \
                tt -= 128;                                             \
            }                                                          \
        }

    float2 X[16];
    LOADX(X);
    __syncthreads();

    // ---- overlap region: routing(slice0) ∥ phase-1(slice1) ----
    const SplitH4 as1a = splitf16v(xf1a);
    const SplitH4 as1b = splitf16v(xf1b);
    const float2 o0 = routing_run(X, [&](int t) {
        const int v0 = ((w4 + t) * 16 + np) ^ (q << 3);
        storeC(u_lds + q * 2048,        v0, mfma3(as1a, bs[t]));
        storeC(u_lds + 8192 + q * 2048, v0, mfma3(as1b, bs[t]));
    });
    *(float2*)(out + ((size_t)b * R_DIM + r) * O_DIM + 2 * j) = o0;

    __syncthreads();

    // ---- tail: routing(slice1), nothing left to overlap ----
    LOADX(X);
    const float2 o1 = routing_run(X, [](int) {});
    *(float2*)(out + ((size_t)(32 + b) * R_DIM + r) * O_DIM + 2 * j) = o1;
    #undef LOADX
}

extern "C" void kernel_launch(void* const* d_in, const int* in_sizes, int n_in,
                              void* d_out, int out_size, void* d_ws, size_t ws_size,
                              hipStream_t stream) {
    const float* x   = (const float*)d_in[0];   // [64, 2048, 16]
    const float* W   = (const float*)d_in[1];   // [2048, 16, 32, 16]
    float*       out = (float*)d_out;           // [64, 2048, 32]

    dim3 grid(R_DIM);                           // 2048 blocks, one r each
    dim3 block(512);
    hipLaunchKernelGGL(capsule_routing_kernel, grid, block, 0, stream, x, W, out);
}